// Round 14
// baseline (620.471 us; speedup 1.0000x reference)
//
#include <hip/hip_runtime.h>

#define TT   2048
#define BSZ  64
#define DD0  256
#define DD1  128
#define DD2  3
#define NROW (DD1*BSZ)   // 8192 rows, r = o*64 + b

typedef unsigned char u8;
typedef __attribute__((ext_vector_type(8))) short short8;
typedef __attribute__((ext_vector_type(4))) float f32x4;
typedef __attribute__((ext_vector_type(4))) unsigned short us4;
typedef __attribute__((ext_vector_type(4))) int i32x4;
typedef __attribute__((ext_vector_type(8))) int i32x8;

__device__ __forceinline__ unsigned short f2b(float f) {
  unsigned u = __builtin_bit_cast(unsigned, f);
  unsigned r = (u + 0x7fffu + ((u >> 16) & 1u)) >> 16;   // RNE
  return (unsigned short)r;
}
__device__ __forceinline__ float b2f(unsigned short s) {
  unsigned u = ((unsigned)s) << 16;
  return __builtin_bit_cast(float, u);
}
__device__ __forceinline__ u8 f2f8(float x) {
  return (u8)(__builtin_amdgcn_cvt_pk_fp8_f32(x, 0.f, 0, false) & 0xff);
}
__device__ __forceinline__ unsigned f2f8x4(float a, float b, float c, float d) {
  int v = __builtin_amdgcn_cvt_pk_fp8_f32(a, b, 0, false);
  v = __builtin_amdgcn_cvt_pk_fp8_f32(c, d, v, true);
  return (unsigned)v;
}

__device__ __forceinline__ void gload16(const void* g, void* l) {
  __builtin_amdgcn_global_load_lds(
      (const __attribute__((address_space(1))) unsigned int*)(unsigned long long)g,
      (__attribute__((address_space(3))) unsigned int*)(unsigned int)(unsigned long long)l,
      16, 0, 0);
}

// --------------------------- transpose + f32 -> fp8 (x8 scale), 4 weights in z
__global__ __launch_bounds__(256) void transpose_cvt8(
    const float* __restrict__ s0, const float* __restrict__ s1,
    const float* __restrict__ s2, const float* __restrict__ s3,
    u8* __restrict__ dst_all)
{
  __shared__ float tile[64 * 65];
  const int z = blockIdx.z;
  const float* src = (z == 0) ? s0 : (z == 1) ? s1 : (z == 2) ? s2 : s3;
  u8* dst = dst_all + (size_t)z * TT * TT;
  const int c0 = blockIdx.x * 64, r0 = blockIdx.y * 64;
  const int tid = threadIdx.x;
#pragma unroll
  for (int i = 0; i < 4; ++i) {
    int e = i * 256 + tid;
    int r = e >> 4, q = e & 15;
    float4 v = *(const float4*)&src[(size_t)(r0 + r) * TT + c0 + q * 4];
    tile[r * 65 + q * 4 + 0] = v.x;
    tile[r * 65 + q * 4 + 1] = v.y;
    tile[r * 65 + q * 4 + 2] = v.z;
    tile[r * 65 + q * 4 + 3] = v.w;
  }
  __syncthreads();
#pragma unroll
  for (int i = 0; i < 4; ++i) {
    int e = i * 256 + tid;
    int c = e >> 4, q = e & 15;
    unsigned v = f2f8x4(tile[(q * 4 + 0) * 65 + c] * 8.f,
                        tile[(q * 4 + 1) * 65 + c] * 8.f,
                        tile[(q * 4 + 2) * 65 + c] * 8.f,
                        tile[(q * 4 + 3) * 65 + c] * 8.f);
    *(unsigned*)&dst[(size_t)(c0 + c) * TT + r0 + q * 4] = v;
  }
}

// -------------------------------------------------------- fused projection
// (round-13 proven) Dout = W1 @ X[b] direct from X; A staged to swizzled LDS.
__global__ __launch_bounds__(256) void proj_kernel(
    const float* __restrict__ W1, const float* __restrict__ X,
    unsigned short* __restrict__ Dout, u8* __restrict__ D8)
{
  __shared__ __align__(16) unsigned short Al[128 * 256];   // 64 KB, XOR-swizzled
  const int tid = threadIdx.x;
  const int b = blockIdx.y, t0 = blockIdx.x * 128;
  const int w = tid >> 6, l = tid & 63;
  const int q4 = l >> 4;

#pragma unroll
  for (int i = 0; i < 16; ++i) {
    int id = i * 256 + tid;
    int row = id >> 5, u = id & 31;
    const float* s = &W1[row * DD0 + u * 8];
    float4 v0 = *(const float4*)s;
    float4 v1 = *(const float4*)(s + 4);
    short8 p;
    p[0] = f2b(v0.x); p[1] = f2b(v0.y); p[2] = f2b(v0.z); p[3] = f2b(v0.w);
    p[4] = f2b(v1.x); p[5] = f2b(v1.y); p[6] = f2b(v1.z); p[7] = f2b(v1.w);
    *(short8*)&Al[row * 256 + ((u ^ (row & 7)) * 8)] = p;
  }
  __syncthreads();

  f32x4 acc[8][2];
#pragma unroll
  for (int m = 0; m < 8; ++m)
#pragma unroll
    for (int n = 0; n < 2; ++n) acc[m][n] = f32x4{0.f, 0.f, 0.f, 0.f};

#pragma unroll 2
  for (int kk = 0; kk < 8; ++kk) {            // K = 256, 32 per step
    const int koff = kk * 32 + q4 * 8;
    short8 bfr[2];
#pragma unroll
    for (int n = 0; n < 2; ++n) {
      const int t = t0 + w * 32 + n * 16 + (l & 15);
      const float* xp = X + (size_t)(b * DD0 + koff) * TT + t;
      short8 p;
#pragma unroll
      for (int j = 0; j < 8; ++j) p[j] = f2b(xp[(size_t)j * TT]);
      bfr[n] = p;
    }
#pragma unroll
    for (int m = 0; m < 8; ++m) {
      int row = m * 16 + (l & 15);
      short8 a = *(const short8*)&Al[row * 256 + (((kk * 4 + q4) ^ (row & 7)) * 8)];
      acc[m][0] = __builtin_amdgcn_mfma_f32_16x16x32_bf16(a, bfr[0], acc[m][0], 0, 0, 0);
      acc[m][1] = __builtin_amdgcn_mfma_f32_16x16x32_bf16(a, bfr[1], acc[m][1], 0, 0, 0);
    }
  }
#pragma unroll
  for (int m = 0; m < 8; ++m)
#pragma unroll
    for (int n = 0; n < 2; ++n)
#pragma unroll
      for (int r = 0; r < 4; ++r) {
        int o = m * 16 + q4 * 4 + r;
        int t = t0 + w * 32 + n * 16 + (l & 15);
        size_t idx = (size_t)(o * BSZ + b) * TT + t;
        float v = acc[m][n][r];
        Dout[idx] = f2b(v);
        D8[idx] = f2f8(v * 8.f);
      }
}

// ------------------------------------------------------------- Y bias init
__global__ __launch_bounds__(256) void init_y(
    const float* __restrict__ Bb, float* __restrict__ Y)
{
  int id = blockIdx.x * 256 + threadIdx.x;
  if (id < BSZ * DD1 * DD2) Y[id] = Bb[id % (DD1 * DD2)];
}

// ----------------------------------------------------------------- DFSMN stage
// MX-scaled fp8, BM=256, BN=256, BK=128; 8 waves (2Mx4N). NEW vs round 11:
// B fragments load DIRECTLY from Wt8 global (L2-resident slice) — per-lane
// contiguous 32 B, no staging/swizzle; B(t+1) prefetched to regs at tile top
// (full-tile landing window, forced by the end-of-tile vmcnt(0)). A stays
// LDS-staged (4x reuse). Removes half the gload_lds and half the LDS reads.
template <int FIRST, int LAST>
__global__ __launch_bounds__(512, 2) void stage_kernel(
    const u8* __restrict__ Din8, const unsigned short* __restrict__ DinBf,
    const u8* __restrict__ Wt8, const unsigned short* DprevBf,
    unsigned short* DoutBf, u8* __restrict__ Dout8,
    const float* __restrict__ W2, float* __restrict__ Y)
{
  __shared__ __align__(16) unsigned short lds[65536];  // 128 KiB (A dbuf 64K + probs 128K reuse)
  char* ldsb = (char*)lds;
  const int tid = threadIdx.x, w = tid >> 6, l = tid & 63;
  const int wr = w >> 2, wc = w & 3;
  const int L = blockIdx.y * 8 + blockIdx.x;           // XCD chunking (8s x 4r)
  const int s0 = ((L >> 3) & 7) * 256;
  const int r0 = ((L & 7) * 4 + (L >> 6)) * 256;
  const u8* DinR = Din8 + (size_t)r0 * TT;
  const u8* WtR  = Wt8 + (size_t)s0 * TT;
  const int q4 = l >> 4;
  const int NT = TT / 128;                             // 16 K-tiles

  f32x4 acc[8][4];
#pragma unroll
  for (int m = 0; m < 8; ++m)
#pragma unroll
    for (int n = 0; n < 4; ++n) acc[m][n] = f32x4{0.f, 0.f, 0.f, 0.f};

  auto STAGE_A = [&](int tau) {                        // 4 gload16/lane/tile
    if (tau >= NT) return;
    const int k0 = tau * 128, buf = tau & 1;
    const int lrow = l >> 3;
    const int swz = ((l & 7) ^ lrow) << 4;             // inverse swizzle on source
#pragma unroll
    for (int c = 0; c < 4; ++c) {
      int ch = w * 4 + c;                              // 32 chunks of 8 rows x 128B
      gload16(DinR + (size_t)(ch * 8 + lrow) * TT + k0 + swz,
              ldsb + buf * 32768 + ch * 1024);
    }
  };
  auto LOADB = [&](int tau, i32x8 (&bb)[4]) {          // 8 dwordx4/lane from L2
    if (tau >= NT) return;
    const int k0 = tau * 128 + q4 * 32;
#pragma unroll
    for (int j = 0; j < 4; ++j) {                      // j = bh*2+n
      int rb = (j >> 1) * 128 + wc * 32 + (j & 1) * 16 + (l & 15);
      const u8* p = WtR + (size_t)rb * TT + k0;
      i32x4 lo = *(const i32x4*)p;
      i32x4 hi = *(const i32x4*)(p + 16);
      bb[j] = __builtin_shufflevector(lo, hi, 0, 1, 2, 3, 4, 5, 6, 7);
    }
  };
  auto LDA = [&](int buf, int ah, i32x8 (&ar)[4]) {
#pragma unroll
    for (int m = 0; m < 4; ++m) {
      int ra = ah * 128 + wr * 64 + m * 16 + (l & 15);
      const char* rowp = ldsb + buf * 32768 + ra * 128;
      i32x4 lo = *(const i32x4*)(rowp + (((q4 * 2 + 0) ^ (ra & 7)) * 16));
      i32x4 hi = *(const i32x4*)(rowp + (((q4 * 2 + 1) ^ (ra & 7)) * 16));
      ar[m] = __builtin_shufflevector(lo, hi, 0, 1, 2, 3, 4, 5, 6, 7);
    }
  };

  i32x8 a[4], bA[4], bB[4];

  auto BODY = [&](int t, i32x8 (&bc)[4], i32x8 (&bn)[4]) {
    const int buf = t & 1;
    STAGE_A(t + 1);               // gload_lds into buf^1
    LOADB(t + 1, bn);             // B(t+1) reg prefetch (L2)
#pragma unroll
    for (int ah = 0; ah < 2; ++ah) {
      LDA(buf, ah, a);
      __builtin_amdgcn_s_setprio(1);
#pragma unroll
      for (int m = 0; m < 4; ++m)
#pragma unroll
        for (int j = 0; j < 4; ++j)
          acc[ah * 4 + m][j] = __builtin_amdgcn_mfma_scale_f32_16x16x128_f8f6f4(
              a[m], bc[j], acc[ah * 4 + m][j],
              0, 0, 0, 0x7f7f7f7f, 0, 0x7f7f7f7f);     // fp8/fp8, scales=1.0
      __builtin_amdgcn_s_setprio(0);
    }
    asm volatile("s_waitcnt vmcnt(0)" ::: "memory");   // A(t+1) in LDS, B(t+1) in regs
    __builtin_amdgcn_s_barrier();
  };

  STAGE_A(0);
  LOADB(0, bA);
  asm volatile("s_waitcnt vmcnt(0)" ::: "memory");
  __builtin_amdgcn_s_barrier();

#pragma unroll 1
  for (int t = 0; t < NT; t += 2) {
    BODY(t, bA, bB);
    BODY(t + 1, bB, bA);
  }

  // ---- epilogue 1: softmax over 64-batch groups (descale /64), probs -> LDS
  const int cc = l & 15;
#pragma unroll
  for (int j = 0; j < 4; ++j) {
    const int bh = j >> 1, nn = j & 1;
    const int col = bh * 128 + wc * 32 + nn * 16 + cc;
    const int u = col >> 3;
#pragma unroll
    for (int ah = 0; ah < 2; ++ah) {
      float mx = -3.0e38f;
#pragma unroll
      for (int m = 0; m < 4; ++m)
#pragma unroll
        for (int r = 0; r < 4; ++r) mx = fmaxf(mx, acc[ah * 4 + m][j][r]);
      mx = fmaxf(mx, __shfl_xor(mx, 16));
      mx = fmaxf(mx, __shfl_xor(mx, 32));
      float pr[4][4];
      float sm = 0.f;
#pragma unroll
      for (int m = 0; m < 4; ++m)
#pragma unroll
        for (int r = 0; r < 4; ++r) {
          pr[m][r] = __expf((acc[ah * 4 + m][j][r] - mx) * 0.015625f);
          sm += pr[m][r];
        }
      sm += __shfl_xor(sm, 16);
      sm += __shfl_xor(sm, 32);
      const float rs = 1.f / sm;
#pragma unroll
      for (int m = 0; m < 4; ++m)
#pragma unroll
        for (int r = 0; r < 4; ++r) {
          int row = ah * 128 + wr * 64 + m * 16 + q4 * 4 + r;
          lds[row * 256 + (((u ^ ((row >> 2) & 7)) << 3) | (col & 7))] = f2b(pr[m][r] * rs);
        }
    }
  }
  asm volatile("s_waitcnt lgkmcnt(0)" ::: "memory");
  __builtin_amdgcn_s_barrier();

  // ---- epilogue 2: coalesced stream. Mprev = Din - Dprev; Mn = D*A + Mprev;
  // Dout = D + Mn. LAST: accumulate Y += D4 @ W2 instead of storing D4.
#pragma unroll 2
  for (int i = 0; i < 16; ++i) {
    int unit = i * 512 + tid;
    int row = unit >> 5, u = unit & 31;
    short8 a8 = *(const short8*)&lds[row * 256 + ((u ^ ((row >> 2) & 7)) << 3)];
    size_t g = (size_t)(r0 + row) * TT + s0 + u * 8;
    short8 d8 = *(const short8*)&DinBf[g];
    short8 dp8 = {};
    if (!FIRST) dp8 = *(const short8*)&DprevBf[g];
    short8 ob;
    float dn[8];
#pragma unroll
    for (int jj = 0; jj < 8; ++jj) {
      float d = b2f((unsigned short)d8[jj]);
      float aa = b2f((unsigned short)a8[jj]);
      float mp = FIRST ? 0.f : (d - b2f((unsigned short)dp8[jj]));
      float mn = fmaf(d, aa, mp);
      dn[jj] = d + mn;
      ob[jj] = (short)f2b(dn[jj]);
    }
    if (!LAST) {
      *(short8*)&DoutBf[g] = ob;
      unsigned w0 = f2f8x4(dn[0] * 8.f, dn[1] * 8.f, dn[2] * 8.f, dn[3] * 8.f);
      unsigned w1 = f2f8x4(dn[4] * 8.f, dn[5] * 8.f, dn[6] * 8.f, dn[7] * 8.f);
      *(unsigned long long*)&Dout8[g] = (unsigned long long)w0 |
                                        ((unsigned long long)w1 << 32);
    } else {
      float p0 = 0.f, p1 = 0.f, p2 = 0.f;
#pragma unroll
      for (int jj = 0; jj < 8; ++jj) {
        const float* w2 = &W2[(size_t)(s0 + u * 8 + jj) * DD2];
        p0 = fmaf(dn[jj], w2[0], p0);
        p1 = fmaf(dn[jj], w2[1], p1);
        p2 = fmaf(dn[jj], w2[2], p2);
      }
#pragma unroll
      for (int off = 1; off < 32; off <<= 1) {
        p0 += __shfl_xor(p0, off);
        p1 += __shfl_xor(p1, off);
        p2 += __shfl_xor(p2, off);
      }
      if ((l & 31) == 0) {
        int gr = r0 + row;                 // = o*64 + b
        int o = gr >> 6, bb = gr & 63;
        float* y = &Y[(size_t)(bb * DD1 + o) * DD2];
        atomicAdd(&y[0], p0);
        atomicAdd(&y[1], p1);
        atomicAdd(&y[2], p2);
      }
    }
  }
}

// -------------------------------------------------------------------- launch
extern "C" void kernel_launch(void* const* d_in, const int* in_sizes, int n_in,
                              void* d_out, int out_size, void* d_ws, size_t ws_size,
                              hipStream_t stream)
{
  const float* X  = (const float*)d_in[0];
  const float* W1 = (const float*)d_in[1];
  const float* DW[4] = {(const float*)d_in[2], (const float*)d_in[3],
                        (const float*)d_in[4], (const float*)d_in[5]};
  const float* W2 = (const float*)d_in[6];
  const float* Bb = (const float*)d_in[7];
  float* Y = (float*)d_out;

  // ws (bytes): [Wt8 x4: 0..16M][Dbf0: 16..48M][D80: 48..64M]
  //             [Dbf1: 64..96M][D81: 96..112M]
  u8* wsb = (u8*)d_ws;
  u8* Wt8all = wsb;
  unsigned short* Dbf0 = (unsigned short*)(wsb + (16ull << 20));
  u8*             D80  = wsb + (48ull << 20);
  unsigned short* Dbf1 = (unsigned short*)(wsb + (64ull << 20));
  u8*             D81  = wsb + (96ull << 20);

  dim3 blk(256);
  transpose_cvt8<<<dim3(TT / 64, TT / 64, 4), blk, 0, stream>>>(
      DW[0], DW[1], DW[2], DW[3], Wt8all);

  proj_kernel<<<dim3(TT / 128, BSZ), blk, 0, stream>>>(W1, X, Dbf0, D80);

  init_y<<<dim3((BSZ * DD1 * DD2 + 255) / 256), blk, 0, stream>>>(Bb, Y);

  dim3 sblk(512);
  dim3 sgrid(TT / 256, NROW / 256);   // 8 x 32 = 256 blocks
  u8* Wt8_0 = Wt8all + 0ull * TT * TT;
  u8* Wt8_1 = Wt8all + 1ull * TT * TT;
  u8* Wt8_2 = Wt8all + 2ull * TT * TT;
  u8* Wt8_3 = Wt8all + 3ull * TT * TT;
  stage_kernel<1, 0><<<sgrid, sblk, 0, stream>>>(D80, Dbf0, Wt8_0, Dbf0, Dbf1, D81, W2, Y);
  stage_kernel<0, 0><<<sgrid, sblk, 0, stream>>>(D81, Dbf1, Wt8_1, Dbf0, Dbf0, D80, W2, Y);
  stage_kernel<0, 0><<<sgrid, sblk, 0, stream>>>(D80, Dbf0, Wt8_2, Dbf1, Dbf1, D81, W2, Y);
  stage_kernel<0, 1><<<sgrid, sblk, 0, stream>>>(D81, Dbf1, Wt8_3, Dbf0, Dbf0, D80, W2, Y);
}

// Round 15
// 264.679 us; speedup vs baseline: 2.3442x; 2.3442x over previous
//
#include <hip/hip_runtime.h>

#define TT   2048
#define BSZ  64
#define DD0  256
#define DD1  128
#define DD2  3
#define NROW (DD1*BSZ)   // 8192 rows, r = o*64 + b

typedef unsigned char u8;
typedef __attribute__((ext_vector_type(8))) short short8;
typedef __attribute__((ext_vector_type(4))) float f32x4;
typedef __attribute__((ext_vector_type(4))) unsigned short us4;
typedef __attribute__((ext_vector_type(4))) int i32x4;
typedef __attribute__((ext_vector_type(8))) int i32x8;

__device__ __forceinline__ unsigned short f2b(float f) {
  unsigned u = __builtin_bit_cast(unsigned, f);
  unsigned r = (u + 0x7fffu + ((u >> 16) & 1u)) >> 16;   // RNE
  return (unsigned short)r;
}
__device__ __forceinline__ float b2f(unsigned short s) {
  unsigned u = ((unsigned)s) << 16;
  return __builtin_bit_cast(float, u);
}
__device__ __forceinline__ u8 f2f8(float x) {
  return (u8)(__builtin_amdgcn_cvt_pk_fp8_f32(x, 0.f, 0, false) & 0xff);
}
__device__ __forceinline__ unsigned f2f8x4(float a, float b, float c, float d) {
  int v = __builtin_amdgcn_cvt_pk_fp8_f32(a, b, 0, false);
  v = __builtin_amdgcn_cvt_pk_fp8_f32(c, d, v, true);
  return (unsigned)v;
}

__device__ __forceinline__ void gload16(const void* g, void* l) {
  __builtin_amdgcn_global_load_lds(
      (const __attribute__((address_space(1))) unsigned int*)(unsigned long long)g,
      (__attribute__((address_space(3))) unsigned int*)(unsigned int)(unsigned long long)l,
      16, 0, 0);
}

// -------------------------------------------- transpose + f32 -> fp8 (x8 scale)
__global__ __launch_bounds__(256) void transpose_cvt8(
    const float* __restrict__ src, u8* __restrict__ dst)
{
  __shared__ float tile[64 * 65];
  const int c0 = blockIdx.x * 64, r0 = blockIdx.y * 64;
  const int tid = threadIdx.x;
#pragma unroll
  for (int i = 0; i < 4; ++i) {
    int e = i * 256 + tid;
    int r = e >> 4, q = e & 15;
    float4 v = *(const float4*)&src[(size_t)(r0 + r) * TT + c0 + q * 4];
    tile[r * 65 + q * 4 + 0] = v.x;
    tile[r * 65 + q * 4 + 1] = v.y;
    tile[r * 65 + q * 4 + 2] = v.z;
    tile[r * 65 + q * 4 + 3] = v.w;
  }
  __syncthreads();
#pragma unroll
  for (int i = 0; i < 4; ++i) {
    int e = i * 256 + tid;
    int c = e >> 4, q = e & 15;
    unsigned v = f2f8x4(tile[(q * 4 + 0) * 65 + c] * 8.f,
                        tile[(q * 4 + 1) * 65 + c] * 8.f,
                        tile[(q * 4 + 2) * 65 + c] * 8.f,
                        tile[(q * 4 + 3) * 65 + c] * 8.f);
    *(unsigned*)&dst[(size_t)(c0 + c) * TT + r0 + q * 4] = v;
  }
}

// -------------------------------------------------------- fused projection
// Dout[(o*64+b)*T + t] = bf16( sum_d W1[o][d] * X[b][d][t] ), no Xt pass:
// A (W1) staged once to swizzled LDS (f32->bf16); B fragments loaded per-lane
// DIRECTLY from X (8 dwords stride TT; lanes 0-15 share 64B segments).
__global__ __launch_bounds__(256) void proj_kernel(
    const float* __restrict__ W1, const float* __restrict__ X,
    unsigned short* __restrict__ Dout, u8* __restrict__ D8)
{
  __shared__ __align__(16) unsigned short Al[128 * 256];   // 64 KB, XOR-swizzled
  const int tid = threadIdx.x;
  const int b = blockIdx.y, t0 = blockIdx.x * 128;
  const int w = tid >> 6, l = tid & 63;
  const int q4 = l >> 4;

#pragma unroll
  for (int i = 0; i < 16; ++i) {
    int id = i * 256 + tid;
    int row = id >> 5, u = id & 31;
    const float* s = &W1[row * DD0 + u * 8];
    float4 v0 = *(const float4*)s;
    float4 v1 = *(const float4*)(s + 4);
    short8 p;
    p[0] = f2b(v0.x); p[1] = f2b(v0.y); p[2] = f2b(v0.z); p[3] = f2b(v0.w);
    p[4] = f2b(v1.x); p[5] = f2b(v1.y); p[6] = f2b(v1.z); p[7] = f2b(v1.w);
    *(short8*)&Al[row * 256 + ((u ^ (row & 7)) * 8)] = p;
  }
  __syncthreads();

  f32x4 acc[8][2];
#pragma unroll
  for (int m = 0; m < 8; ++m)
#pragma unroll
    for (int n = 0; n < 2; ++n) acc[m][n] = f32x4{0.f, 0.f, 0.f, 0.f};

#pragma unroll 2
  for (int kk = 0; kk < 8; ++kk) {            // K = 256, 32 per step
    const int koff = kk * 32 + q4 * 8;
    short8 bfr[2];
#pragma unroll
    for (int n = 0; n < 2; ++n) {
      const int t = t0 + w * 32 + n * 16 + (l & 15);
      const float* xp = X + (size_t)(b * DD0 + koff) * TT + t;
      short8 p;
#pragma unroll
      for (int j = 0; j < 8; ++j) p[j] = f2b(xp[(size_t)j * TT]);
      bfr[n] = p;
    }
#pragma unroll
    for (int m = 0; m < 8; ++m) {
      int row = m * 16 + (l & 15);
      short8 a = *(const short8*)&Al[row * 256 + (((kk * 4 + q4) ^ (row & 7)) * 8)];
      acc[m][0] = __builtin_amdgcn_mfma_f32_16x16x32_bf16(a, bfr[0], acc[m][0], 0, 0, 0);
      acc[m][1] = __builtin_amdgcn_mfma_f32_16x16x32_bf16(a, bfr[1], acc[m][1], 0, 0, 0);
    }
  }
#pragma unroll
  for (int m = 0; m < 8; ++m)
#pragma unroll
    for (int n = 0; n < 2; ++n)
#pragma unroll
      for (int r = 0; r < 4; ++r) {
        int o = m * 16 + q4 * 4 + r;
        int t = t0 + w * 32 + n * 16 + (l & 15);
        size_t idx = (size_t)(o * BSZ + b) * TT + t;
        float v = acc[m][n][r];
        Dout[idx] = f2b(v);
        D8[idx] = f2f8(v * 8.f);
      }
}

// ------------------------------------------------------------- Y bias init
__global__ __launch_bounds__(256) void init_y(
    const float* __restrict__ Bb, float* __restrict__ Y)
{
  int id = blockIdx.x * 256 + threadIdx.x;
  if (id < BSZ * DD1 * DD2) Y[id] = Bb[id % (DD1 * DD2)];
}

// ----------------------------------------------------------------- DFSMN stage
// ROUND-11 GEMM verbatim (proven): MX-scaled fp8, BM=256, BN=256, BK=128;
// 512 thr = 8 waves (2Mx4N); minimal-sync loop, NT=16. M-elim epilogue.
// LAST=1: fuse output projection — accumulate Y += D4 @ W2 via per-row
// shuffle-reduce + atomicAdd; skip DoutBf/Dout8 stores.
template <int FIRST, int LAST>
__global__ __launch_bounds__(512, 2) void stage_kernel(
    const u8* __restrict__ Din8, const unsigned short* __restrict__ DinBf,
    const u8* __restrict__ Wt8, const unsigned short* DprevBf,
    unsigned short* DoutBf, u8* __restrict__ Dout8,
    const float* __restrict__ W2, float* __restrict__ Y)
{
  __shared__ __align__(16) unsigned short lds[65536];  // 128 KiB
  char* ldsb = (char*)lds;
  const int tid = threadIdx.x, w = tid >> 6, l = tid & 63;
  const int wr = w >> 2, wc = w & 3;
  const int L = blockIdx.y * 8 + blockIdx.x;           // XCD chunking (8s x 4r)
  const int s0 = ((L >> 3) & 7) * 256;
  const int r0 = ((L & 7) * 4 + (L >> 6)) * 256;
  const u8* DinR = Din8 + (size_t)r0 * TT;
  const u8* WtR  = Wt8 + (size_t)s0 * TT;
  const int q4 = l >> 4;
  const int NT = TT / 128;                             // 16 K-tiles

  f32x4 acc[8][4];
#pragma unroll
  for (int m = 0; m < 8; ++m)
#pragma unroll
    for (int n = 0; n < 4; ++n) acc[m][n] = f32x4{0.f, 0.f, 0.f, 0.f};

  auto STAGE = [&](int tau) {                          // 8 gload16/lane/tile
    if (tau >= NT) return;
    const int k0 = tau * 128, buf = tau & 1;
    const int lrow = l >> 3;
    const int swz = ((l & 7) ^ lrow) << 4;             // inverse swizzle on source
#pragma unroll
    for (int c = 0; c < 8; ++c) {
      int ch = w * 8 + c;                              // 0..63: 0-31 A, 32-63 B
      const u8* base = (ch & 32) ? WtR : DinR;
      int cc = ch & 31;                                // chunk = 8 rows x 128B
      gload16(base + (size_t)(cc * 8 + lrow) * TT + k0 + swz,
              ldsb + ((ch & 32) ? 65536 : 0) + buf * 32768 + cc * 1024);
    }
  };
  auto LDA = [&](int buf, int ah, i32x8 (&ar)[4]) {
#pragma unroll
    for (int m = 0; m < 4; ++m) {
      int ra = ah * 128 + wr * 64 + m * 16 + (l & 15);
      const char* rowp = ldsb + buf * 32768 + ra * 128;
      i32x4 lo = *(const i32x4*)(rowp + (((q4 * 2 + 0) ^ (ra & 7)) * 16));
      i32x4 hi = *(const i32x4*)(rowp + (((q4 * 2 + 1) ^ (ra & 7)) * 16));
      ar[m] = __builtin_shufflevector(lo, hi, 0, 1, 2, 3, 4, 5, 6, 7);
    }
  };
  auto LDB = [&](int buf, int bh, i32x8 (&br)[2]) {
#pragma unroll
    for (int n = 0; n < 2; ++n) {
      int rb = bh * 128 + wc * 32 + n * 16 + (l & 15);
      const char* rowp = ldsb + 65536 + buf * 32768 + rb * 128;
      i32x4 lo = *(const i32x4*)(rowp + (((q4 * 2 + 0) ^ (rb & 7)) * 16));
      i32x4 hi = *(const i32x4*)(rowp + (((q4 * 2 + 1) ^ (rb & 7)) * 16));
      br[n] = __builtin_shufflevector(lo, hi, 0, 1, 2, 3, 4, 5, 6, 7);
    }
  };
  auto MM = [&](int ah, int bh, i32x8 (&ar)[4], i32x8 (&br)[2]) {
    __builtin_amdgcn_s_setprio(1);
#pragma unroll
    for (int m = 0; m < 4; ++m)
#pragma unroll
      for (int n = 0; n < 2; ++n)
        acc[ah * 4 + m][bh * 2 + n] =
            __builtin_amdgcn_mfma_scale_f32_16x16x128_f8f6f4(
                ar[m], br[n], acc[ah * 4 + m][bh * 2 + n],
                0, 0, 0, 0x7f7f7f7f, 0, 0x7f7f7f7f);   // fp8/fp8, scales=1.0
    __builtin_amdgcn_s_setprio(0);
  };

  i32x8 a[4], b0[2], b1[2];

  STAGE(0);
  asm volatile("s_waitcnt vmcnt(0)" ::: "memory");
  __builtin_amdgcn_s_barrier();

#pragma unroll 1
  for (int t = 0; t < NT; ++t) {
    const int buf = t & 1;
    STAGE(t + 1);                 // into buf^1; landing window = full tile
    LDB(buf, 0, b0);
    LDA(buf, 0, a);
    LDB(buf, 1, b1);
    MM(0, 0, a, b0);
    MM(0, 1, a, b1);
    LDA(buf, 1, a);               // ah=0 frags dead; reuse regs
    MM(1, 1, a, b1);
    MM(1, 0, a, b0);
    asm volatile("s_waitcnt vmcnt(0)" ::: "memory");
    __builtin_amdgcn_s_barrier();
  }

  // ---- epilogue 1: softmax over 64-batch groups (descale /64), probs -> LDS
  const int cc = l & 15;
#pragma unroll
  for (int j = 0; j < 4; ++j) {
    const int bh = j >> 1, nn = j & 1;
    const int col = bh * 128 + wc * 32 + nn * 16 + cc;
    const int u = col >> 3;
#pragma unroll
    for (int ah = 0; ah < 2; ++ah) {
      float mx = -3.0e38f;
#pragma unroll
      for (int m = 0; m < 4; ++m)
#pragma unroll
        for (int r = 0; r < 4; ++r) mx = fmaxf(mx, acc[ah * 4 + m][j][r]);
      mx = fmaxf(mx, __shfl_xor(mx, 16));
      mx = fmaxf(mx, __shfl_xor(mx, 32));
      float pr[4][4];
      float sm = 0.f;
#pragma unroll
      for (int m = 0; m < 4; ++m)
#pragma unroll
        for (int r = 0; r < 4; ++r) {
          pr[m][r] = __expf((acc[ah * 4 + m][j][r] - mx) * 0.015625f);
          sm += pr[m][r];
        }
      sm += __shfl_xor(sm, 16);
      sm += __shfl_xor(sm, 32);
      const float rs = 1.f / sm;
#pragma unroll
      for (int m = 0; m < 4; ++m)
#pragma unroll
        for (int r = 0; r < 4; ++r) {
          int row = ah * 128 + wr * 64 + m * 16 + q4 * 4 + r;
          lds[row * 256 + (((u ^ ((row >> 2) & 7)) << 3) | (col & 7))] = f2b(pr[m][r] * rs);
        }
    }
  }
  asm volatile("s_waitcnt lgkmcnt(0)" ::: "memory");
  __builtin_amdgcn_s_barrier();

  // ---- epilogue 2: coalesced stream. Mprev = Din - Dprev; Mn = D*A + Mprev;
  // Dout = D + Mn. LAST: accumulate Y += D4 @ W2 instead of storing D4.
#pragma unroll 2
  for (int i = 0; i < 16; ++i) {
    int unit = i * 512 + tid;
    int row = unit >> 5, u = unit & 31;
    short8 a8 = *(const short8*)&lds[row * 256 + ((u ^ ((row >> 2) & 7)) << 3)];
    size_t g = (size_t)(r0 + row) * TT + s0 + u * 8;
    short8 d8 = *(const short8*)&DinBf[g];
    short8 dp8 = {};
    if (!FIRST) dp8 = *(const short8*)&DprevBf[g];
    short8 ob;
    float dn[8];
#pragma unroll
    for (int jj = 0; jj < 8; ++jj) {
      float d = b2f((unsigned short)d8[jj]);
      float aa = b2f((unsigned short)a8[jj]);
      float mp = FIRST ? 0.f : (d - b2f((unsigned short)dp8[jj]));
      float mn = fmaf(d, aa, mp);
      dn[jj] = d + mn;
      ob[jj] = (short)f2b(dn[jj]);
    }
    if (!LAST) {
      *(short8*)&DoutBf[g] = ob;
      unsigned w0 = f2f8x4(dn[0] * 8.f, dn[1] * 8.f, dn[2] * 8.f, dn[3] * 8.f);
      unsigned w1 = f2f8x4(dn[4] * 8.f, dn[5] * 8.f, dn[6] * 8.f, dn[7] * 8.f);
      *(unsigned long long*)&Dout8[g] = (unsigned long long)w0 |
                                        ((unsigned long long)w1 << 32);
    } else {
      // partial Y for this row over 8 t-cols
      float p0 = 0.f, p1 = 0.f, p2 = 0.f;
#pragma unroll
      for (int jj = 0; jj < 8; ++jj) {
        const float* w2 = &W2[(size_t)(s0 + u * 8 + jj) * DD2];
        p0 = fmaf(dn[jj], w2[0], p0);
        p1 = fmaf(dn[jj], w2[1], p1);
        p2 = fmaf(dn[jj], w2[2], p2);
      }
      // reduce over the 32 consecutive threads sharing this row
#pragma unroll
      for (int off = 1; off < 32; off <<= 1) {
        p0 += __shfl_xor(p0, off);
        p1 += __shfl_xor(p1, off);
        p2 += __shfl_xor(p2, off);
      }
      if ((l & 31) == 0) {
        int gr = r0 + row;                 // = o*64 + b
        int o = gr >> 6, bb = gr & 63;
        float* y = &Y[(size_t)(bb * DD1 + o) * DD2];
        atomicAdd(&y[0], p0);
        atomicAdd(&y[1], p1);
        atomicAdd(&y[2], p2);
      }
    }
  }
}

// -------------------------------------------------------------------- launch
extern "C" void kernel_launch(void* const* d_in, const int* in_sizes, int n_in,
                              void* d_out, int out_size, void* d_ws, size_t ws_size,
                              hipStream_t stream)
{
  const float* X  = (const float*)d_in[0];
  const float* W1 = (const float*)d_in[1];
  const float* DW[4] = {(const float*)d_in[2], (const float*)d_in[3],
                        (const float*)d_in[4], (const float*)d_in[5]};
  const float* W2 = (const float*)d_in[6];
  const float* Bb = (const float*)d_in[7];
  float* Y = (float*)d_out;

  // ws (bytes): [Wt8 x4: 0..16M][Dbf0: 16..48M][D80: 48..64M]
  //             [Dbf1: 64..96M][D81: 96..112M]
  u8* wsb = (u8*)d_ws;
  u8* Wt8[4];
  for (int i = 0; i < 4; ++i) Wt8[i] = wsb + (size_t)i * TT * TT;
  unsigned short* Dbf0 = (unsigned short*)(wsb + (16ull << 20));
  u8*             D80  = wsb + (48ull << 20);
  unsigned short* Dbf1 = (unsigned short*)(wsb + (64ull << 20));
  u8*             D81  = wsb + (96ull << 20);

  dim3 blk(256);
  for (int i = 0; i < 4; ++i)
    transpose_cvt8<<<dim3(TT / 64, TT / 64), blk, 0, stream>>>(DW[i], Wt8[i]);

  proj_kernel<<<dim3(TT / 128, BSZ), blk, 0, stream>>>(W1, X, Dbf0, D80);

  init_y<<<dim3((BSZ * DD1 * DD2 + 255) / 256), blk, 0, stream>>>(Bb, Y);

  dim3 sblk(512);
  dim3 sgrid(TT / 256, NROW / 256);   // 8 x 32 = 256 blocks (round-11 proven)
  stage_kernel<1, 0><<<sgrid, sblk, 0, stream>>>(D80, Dbf0, Wt8[0], Dbf0, Dbf1, D81, W2, Y);
  stage_kernel<0, 0><<<sgrid, sblk, 0, stream>>>(D81, Dbf1, Wt8[1], Dbf0, Dbf0, D80, W2, Y);
  stage_kernel<0, 0><<<sgrid, sblk, 0, stream>>>(D80, Dbf0, Wt8[2], Dbf1, Dbf1, D81, W2, Y);
  stage_kernel<0, 1><<<sgrid, sblk, 0, stream>>>(D81, Dbf1, Wt8[3], Dbf0, Dbf0, D80, W2, Y);
}